// Round 11
// baseline (178.798 us; speedup 1.0000x reference)
//
#include <hip/hip_runtime.h>
#include <hip/hip_bf16.h>

#define BT_TOTAL 1024

typedef __bf16 bf16x8 __attribute__((ext_vector_type(8)));
typedef float  f32x4  __attribute__((ext_vector_type(4)));
typedef int    i32x4  __attribute__((ext_vector_type(4)));
typedef short  s16x4  __attribute__((ext_vector_type(4)));

__device__ inline unsigned short f2bf(float f) {
    unsigned int u = __builtin_bit_cast(unsigned int, f);
    u = (u + 0x7FFFu + ((u >> 16) & 1u)) >> 16;
    return (unsigned short)u;
}

__device__ inline bf16x8 ldsb8(const unsigned short* p) {
    i32x4 t = *(const i32x4*)p;
    return __builtin_bit_cast(bf16x8, t);
}

__device__ __forceinline__ void gl_lds16(const void* g, void* l) {
    __builtin_amdgcn_global_load_lds(
        (const __attribute__((address_space(1))) void*)g,
        (__attribute__((address_space(3))) void*)l, 16, 0, 0);
}

// Per-step sync (r10-proven): WAR fence (own reads done), counted vmcnt
// (prior own-tile stage retired; strays only make it conservative), raw barrier
// (publishes all waves' tile-t bytes). Each wave stages EXACTLY the slice it
// reads -> per-wave lgkmcnt guards the overwrite (r7 lesson).
#define STEP_PRE() do { \
    asm volatile("s_waitcnt lgkmcnt(0)" ::: "memory"); \
    __builtin_amdgcn_sched_barrier(0); } while (0)
#define STEP_POST2() do { \
    asm volatile("s_waitcnt vmcnt(2)" ::: "memory"); \
    __builtin_amdgcn_sched_barrier(0); \
    __builtin_amdgcn_s_barrier(); } while (0)
#define STEP_POST1() do { \
    asm volatile("s_waitcnt vmcnt(1)" ::: "memory"); \
    __builtin_amdgcn_sched_barrier(0); \
    __builtin_amdgcn_s_barrier(); } while (0)
#define STEP_POST0() do { \
    asm volatile("s_waitcnt vmcnt(0)" ::: "memory"); \
    __builtin_amdgcn_sched_barrier(0); \
    __builtin_amdgcn_s_barrier(); } while (0)

// swizzled byte offset of element (n, kl) inside a [N][32] bf16 chunk
__device__ __forceinline__ int swz_off(int n, int kl) {
    return ((n >> 1) << 7) + ((((n & 1) << 6) | (kl << 1)) ^ (((n >> 1) & 7) << 4));
}

template<int CALLS>
__device__ __forceinline__ void stage_tile(const void* chunk, char* dst, int wv, int lane) {
#pragma unroll
    for (int c = 0; c < CALLS; ++c) {
        int off = wv * (CALLS * 1024) + c * 1024;   // wave-private slice == read region
        gl_lds16((const char*)chunk + off + lane * 16, dst + off);
    }
}

// ---------------- prep: weights -> swizzled bf16 chunks (unchanged, verified) ----------------
__global__ __launch_bounds__(512) void prep_weights(
    const float* __restrict__ W1, const float* __restrict__ W2,
    const float* __restrict__ W3,
    unsigned short* __restrict__ wt1, unsigned short* __restrict__ wt2,
    unsigned short* __restrict__ wt3)
{
    int b = blockIdx.x, tid = threadIdx.x;
    if (b < 4) {                    // L1: K=128, N=512
        int k0 = b * 32;
        unsigned short* d = wt1 + b * 16384;
        for (int kl = 0; kl < 32; ++kl) {
            int n = tid;
            float v = W1[(size_t)(k0 + kl) * 512 + n];
            d[swz_off(n, kl) >> 1] = f2bf(v);
        }
    } else if (b < 20) {            // L2: K=512, N=512
        int c = b - 4, k0 = c * 32;
        unsigned short* d = wt2 + c * 16384;
        for (int kl = 0; kl < 32; ++kl) {
            int n = tid;
            float v = W2[(size_t)(k0 + kl) * 512 + n];
            d[swz_off(n, kl) >> 1] = f2bf(v);
        }
    } else {                        // L3: K=512, N=256 (16 chunks)
        int c = b - 20, k0 = c * 32;
        unsigned short* d = wt3 + c * 8192;
        for (int i = 0; i < 16; ++i) {
            int e = i * 512 + tid;
            int kl = e >> 8, n = e & 255;
            float v = W3[(size_t)(k0 + kl) * 256 + n];
            d[swz_off(n, kl) >> 1] = f2bf(v);
        }
    }
}

// ======================= K1: fused MLP, 16 waves (4/SIMD) =======================
// LDS: H [64][520]us @0 (66560) ; B0 @66560 (32768) ; B1 @99328 (32768) -> 132096
// EMB overlay [64][264]us @0 (post-L3)
#define K1_LDS 132096

__global__ __launch_bounds__(1024, 4) void mlp_kernel(
    const float* __restrict__ obs,
    const unsigned short* __restrict__ C1, const float* __restrict__ b1,
    const unsigned short* __restrict__ C2, const float* __restrict__ b2,
    const unsigned short* __restrict__ C3, const float* __restrict__ b3,
    unsigned short* __restrict__ embOut)   // per bt: RM [64][256] then CM [256][64]
{
    extern __shared__ __align__(16) char smem[];
    unsigned short* H   = (unsigned short*)smem;            // [64][520]
    char* B0 = smem + 66560;
    char* B1 = smem + 99328;
    unsigned short* EMB = (unsigned short*)smem;            // [64][264] (post)

    const int bt = blockIdx.x, tid = threadIdx.x;
    const int lane = tid & 63, wv = tid >> 6;   // 16 waves, wave owns 32-col stripe
    const int l16 = lane & 15, l4 = lane >> 4;

    // B-fragment swizzled byte offsets; region == own stage slice
    int boff[2], boff3;
#pragma unroll
    for (int nt = 0; nt < 2; ++nt) {
        int n = wv * 32 + nt * 16 + l16;
        boff[nt] = ((n >> 1) << 7) + ((((n & 1) << 6) | (l4 << 4)) ^ (((n >> 1) & 7) << 4));
    }
    {
        int n = wv * 16 + l16;
        boff3 = ((n >> 1) << 7) + ((((n & 1) << 6) | (l4 << 4)) ^ (((n >> 1) & 7) << 4));
    }

    // biases in registers (drained by prologue __syncthreads)
    float bias1[2], bias2[2], bias3;
#pragma unroll
    for (int nt = 0; nt < 2; ++nt) {
        bias1[nt] = b1[wv * 32 + nt * 16 + l16];
        bias2[nt] = b2[wv * 32 + nt * 16 + l16];
    }
    bias3 = b3[wv * 16 + l16];

    const float* obsG = obs + (size_t)bt * 8192;

    // ---- prologue: stage L1 tile 0 ----
    stage_tile<2>(C1, B0, wv, lane);
    __syncthreads();   // full drain: tile0 + bias loads complete

    // ---- L1: 4 steps, A direct from obs (L1-cache resident) ----
    f32x4 acc1[4][2] = {};
    for (int t = 0; t < 4; ++t) {
        STEP_PRE();
        if (t < 3) stage_tile<2>(C1 + (size_t)(t + 1) * 16384, (t & 1) ? B0 : B1, wv, lane);
        else       stage_tile<2>(C2, B0, wv, lane);
        STEP_POST2();
        const char* bb = (t & 1) ? B1 : B0;
        bf16x8 afr[4], bfr[2];
#pragma unroll
        for (int mt = 0; mt < 4; ++mt) {
            const float* pp = obsG + (mt * 16 + l16) * 128 + t * 32 + l4 * 8;
            f32x4 v0 = *(const f32x4*)(pp);
            f32x4 v1 = *(const f32x4*)(pp + 4);
            bf16x8 a;
            a[0]=(__bf16)v0.x; a[1]=(__bf16)v0.y; a[2]=(__bf16)v0.z; a[3]=(__bf16)v0.w;
            a[4]=(__bf16)v1.x; a[5]=(__bf16)v1.y; a[6]=(__bf16)v1.z; a[7]=(__bf16)v1.w;
            afr[mt] = a;
        }
#pragma unroll
        for (int nt = 0; nt < 2; ++nt)
            bfr[nt] = ldsb8((const unsigned short*)(bb + boff[nt]));
        __builtin_amdgcn_s_setprio(1);
#pragma unroll
        for (int nt = 0; nt < 2; ++nt)
#pragma unroll
            for (int mt = 0; mt < 4; ++mt)
                acc1[mt][nt] = __builtin_amdgcn_mfma_f32_16x16x32_bf16(afr[mt], bfr[nt], acc1[mt][nt], 0, 0, 0);
        __builtin_amdgcn_s_setprio(0);
    }
    {
#pragma unroll
        for (int nt = 0; nt < 2; ++nt) {
            int col = wv * 32 + nt * 16 + l16;
#pragma unroll
            for (int mt = 0; mt < 4; ++mt)
#pragma unroll
                for (int i = 0; i < 4; ++i) {
                    int row = mt * 16 + l4 * 4 + i;
                    H[row * 520 + col] = f2bf(fmaxf(acc1[mt][nt][i] + bias1[nt], 0.f));
                }
        }
    }
    __syncthreads();   // H1 visible; drains C2-tile0 stage

    // ---- L2: 16 steps ----
    f32x4 acc2[4][2] = {};
    for (int t = 0; t < 16; ++t) {
        STEP_PRE();
        if (t < 15) { stage_tile<2>(C2 + (size_t)(t + 1) * 16384, (t & 1) ? B0 : B1, wv, lane); STEP_POST2(); }
        else        { stage_tile<1>(C3, B0, wv, lane);                                          STEP_POST1(); }
        const char* bb = (t & 1) ? B1 : B0;
        bf16x8 afr[4], bfr[2];
#pragma unroll
        for (int mt = 0; mt < 4; ++mt)
            afr[mt] = ldsb8(H + (mt * 16 + l16) * 520 + t * 32 + l4 * 8);
#pragma unroll
        for (int nt = 0; nt < 2; ++nt)
            bfr[nt] = ldsb8((const unsigned short*)(bb + boff[nt]));
        __builtin_amdgcn_s_setprio(1);
#pragma unroll
        for (int nt = 0; nt < 2; ++nt)
#pragma unroll
            for (int mt = 0; mt < 4; ++mt)
                acc2[mt][nt] = __builtin_amdgcn_mfma_f32_16x16x32_bf16(afr[mt], bfr[nt], acc2[mt][nt], 0, 0, 0);
        __builtin_amdgcn_s_setprio(0);
    }
    __syncthreads();   // all H1 reads done before overwrite; drains C3-tile0
    {
#pragma unroll
        for (int nt = 0; nt < 2; ++nt) {
            int col = wv * 32 + nt * 16 + l16;
#pragma unroll
            for (int mt = 0; mt < 4; ++mt)
#pragma unroll
                for (int i = 0; i < 4; ++i) {
                    int row = mt * 16 + l4 * 4 + i;
                    H[row * 520 + col] = f2bf(fmaxf(acc2[mt][nt][i] + bias2[nt], 0.f));
                }
        }
    }
    __syncthreads();   // H2 visible

    // ---- L3: 16 steps (K=512), N=256: wave owns 16-col stripe ----
    f32x4 acc3[4] = {};
    for (int t = 0; t < 16; ++t) {
        STEP_PRE();
        if (t < 15) { stage_tile<1>(C3 + (size_t)(t + 1) * 8192, (t & 1) ? B0 : B1, wv, lane); STEP_POST1(); }
        else        { STEP_POST0(); }
        const char* bb = (t & 1) ? B1 : B0;
        bf16x8 afr[4];
#pragma unroll
        for (int mt = 0; mt < 4; ++mt)
            afr[mt] = ldsb8(H + (mt * 16 + l16) * 520 + t * 32 + l4 * 8);
        bf16x8 bfr = ldsb8((const unsigned short*)(bb + boff3));
        __builtin_amdgcn_s_setprio(1);
#pragma unroll
        for (int mt = 0; mt < 4; ++mt)
            acc3[mt] = __builtin_amdgcn_mfma_f32_16x16x32_bf16(afr[mt], bfr, acc3[mt], 0, 0, 0);
        __builtin_amdgcn_s_setprio(0);
    }
    __syncthreads();   // all H reads done; EMB overlay writable

    // ---- emb epilogue: bf16 tile in LDS, then global RM + CM writes ----
    {
        int col = wv * 16 + l16;
#pragma unroll
        for (int mt = 0; mt < 4; ++mt)
#pragma unroll
            for (int i = 0; i < 4; ++i) {
                int row = mt * 16 + l4 * 4 + i;
                EMB[row * 264 + col] = f2bf(acc3[mt][i] + bias3);
            }
    }
    __syncthreads();
    {
        unsigned short* eR = embOut + (size_t)bt * 32768;
        unsigned short* eC = eR + 16384;
        // RM: [64][256] = 2048 x 16B groups (coalesced)
#pragma unroll
        for (int u = 0; u < 2; ++u) {
            int uu = tid + u * 1024;                // 0..2047
            int row = uu >> 5, c8 = (uu & 31) * 8;
            i32x4 v = *(const i32x4*)(EMB + row * 264 + c8);
            *(i32x4*)(eR + uu * 8) = v;             // eR[row*256 + c8]
        }
        // CM: lane <-> column-consecutive (2-way LDS reads, free)
#pragma unroll
        for (int u = 0; u < 2; ++u) {
            int v = tid + u * 1024;                 // 0..2047
            int col = v & 255, rg = v >> 8;
            i32x4 w;
#pragma unroll
            for (int j = 0; j < 4; ++j) {
                unsigned int a = EMB[(rg * 8 + 2 * j) * 264 + col];
                unsigned int b = EMB[(rg * 8 + 2 * j + 1) * 264 + col];
                w[j] = (int)(a | (b << 16));
            }
            *(i32x4*)(eC + col * 64 + rg * 8) = w;  // eC[col*64 + rg*8]
        }
    }
}

// ======================= K2: attention (unchanged, verified) =======================
// LDS: W1A [16][72]us @0 (2304) ; TCM [256][40]us @2304 (20480) ;
//      TF [16][260]f32 @22784 (16640) ; W2A [64][40]us @39424 (5120) ;
//      MK [64]i32 @44544 (256) ; SMX/SSM @44800 (512) ; TQ [16][264]us @45312 (8448)
#define K2_LDS 53760

__global__ void attn_kernel(const int* __restrict__ amask,
                            const float* __restrict__ tq,
                            const unsigned short* __restrict__ emb,
                            float* __restrict__ outT, float* __restrict__ outC)
{
    extern __shared__ __align__(16) char smem[];
    unsigned short* W1A = (unsigned short*)smem;
    unsigned short* TCM = (unsigned short*)(smem + 2304);
    float*          TF  = (float*)(smem + 22784);
    unsigned short* W2A = (unsigned short*)(smem + 39424);
    int*            MK  = (int*)(smem + 44544);
    float*          SMX = (float*)(smem + 44800);
    float*          SSM = SMX + 64;
    unsigned short* TQ  = (unsigned short*)(smem + 45312);  // [16][264]

    const int bt = blockIdx.x, tid = threadIdx.x;
    const int lane = tid & 63, w = tid >> 6;
    const int l16 = lane & 15, l4 = lane >> 4;
    const unsigned short* eR = emb + (size_t)bt * 32768;
    const unsigned short* eC = eR + 16384;

    if (tid < 64) MK[tid] = amask[(size_t)bt * 64 + tid];
#pragma unroll
    for (int i = 0; i < 16; ++i) {
        int idx = tid + i * 256;
        int row = idx >> 8, col = idx & 255;
        TQ[row * 264 + col] = f2bf(tq[idx]);
    }
    __syncthreads();

    float sv[4]; int msk;
    {
        f32x4 acc = {};
#pragma unroll
        for (int kk = 0; kk < 8; ++kk) {
            int ko = kk*32 + l4*8;
            bf16x8 a = ldsb8(TQ + l16 * 264 + ko);
            bf16x8 b = ldsb8(eR + (w*16 + l16) * 256 + ko);
            acc = __builtin_amdgcn_mfma_f32_16x16x32_bf16(a, b, acc, 0, 0, 0);
        }
        msk = MK[w*16 + l16];
#pragma unroll
        for (int i = 0; i < 4; ++i) sv[i] = msk ? acc[i] * 0.0625f : -3.0e38f;
        float mx[4];
#pragma unroll
        for (int i = 0; i < 4; ++i) {
            float m = sv[i];
#pragma unroll
            for (int off = 1; off < 16; off <<= 1) m = fmaxf(m, __shfl_xor(m, off, 16));
            mx[i] = m;
        }
        if (l16 == 0) {
#pragma unroll
            for (int i = 0; i < 4; ++i) SMX[(l4*4 + i) * 4 + w] = mx[i];
        }
    }
    __syncthreads();
    float ev[4];
    {
#pragma unroll
        for (int i = 0; i < 4; ++i) {
            int q = l4*4 + i;
            float g = fmaxf(fmaxf(SMX[q*4+0], SMX[q*4+1]), fmaxf(SMX[q*4+2], SMX[q*4+3]));
            ev[i] = msk ? __expf(sv[i] - g) : 0.f;
            float s = ev[i];
#pragma unroll
            for (int off = 1; off < 16; off <<= 1) s += __shfl_xor(s, off, 16);
            if (l16 == 0) SSM[q*4 + w] = s;
        }
    }
    __syncthreads();
    {
#pragma unroll
        for (int i = 0; i < 4; ++i) {
            int q = l4*4 + i;
            float tot = SSM[q*4+0] + SSM[q*4+1] + SSM[q*4+2] + SSM[q*4+3];
            float w1 = ev[i] * (1.0f / fmaxf(tot, 1e-8f));
            W1A[q * 72 + w*16 + l16] = f2bf(w1);
        }
    }
    __syncthreads();

    {
        bf16x8 bW[2];
#pragma unroll
        for (int kk = 0; kk < 2; ++kk) bW[kk] = ldsb8(W1A + l16 * 72 + kk*32 + l4*8);
#pragma unroll
        for (int p = 0; p < 4; ++p) {
            int dt = w + p * 4;
            f32x4 acc = {};
#pragma unroll
            for (int kk = 0; kk < 2; ++kk) {
                bf16x8 a = ldsb8(eC + (dt*16 + l16) * 64 + kk*32 + l4*8);
                acc = __builtin_amdgcn_mfma_f32_16x16x32_bf16(a, bW[kk], acc, 0, 0, 0);
            }
#pragma unroll
            for (int i = 0; i < 4; ++i) {
                int d = dt*16 + l4*4 + i;
                TCM[d * 40 + l16]      = f2bf(acc[i]);
                TCM[d * 40 + 16 + l16] = 0;
                TF[l16 * 260 + d]      = acc[i];
            }
        }
    }
    __syncthreads();

    {
        float* oT = outT + (size_t)bt * 4096;
#pragma unroll
        for (int it = 0; it < 16; ++it) {
            int idx = tid + it * 256;
            oT[idx] = TF[(idx >> 8) * 260 + (idx & 255)];
        }
    }

    {
        f32x4 acc = {};
#pragma unroll
        for (int kk = 0; kk < 8; ++kk) {
            int ko = kk*32 + l4*8;
            bf16x8 a = ldsb8(eR + (w*16 + l16) * 256 + ko);
            const float* tp = TF + l16 * 260 + ko;
            f32x4 t0 = *(const f32x4*)tp;
            f32x4 t1 = *(const f32x4*)(tp + 4);
            bf16x8 b;
            b[0]=(__bf16)t0.x; b[1]=(__bf16)t0.y; b[2]=(__bf16)t0.z; b[3]=(__bf16)t0.w;
            b[4]=(__bf16)t1.x; b[5]=(__bf16)t1.y; b[6]=(__bf16)t1.z; b[7]=(__bf16)t1.w;
            acc = __builtin_amdgcn_mfma_f32_16x16x32_bf16(a, b, acc, 0, 0, 0);
        }
#pragma unroll
        for (int i = 0; i < 4; ++i) {
            float s = acc[i] * 0.0625f;
            float m = s;
#pragma unroll
            for (int off = 1; off < 16; off <<= 1) m = fmaxf(m, __shfl_xor(m, off, 16));
            float e = __expf(s - m);
            float su = e;
#pragma unroll
            for (int off = 1; off < 16; off <<= 1) su += __shfl_xor(su, off, 16);
            float w2 = e / su;
            int ag = w*16 + l4*4 + i;
            W2A[ag * 40 + l16]      = f2bf(w2);
            W2A[ag * 40 + 16 + l16] = 0;
        }
    }
    __syncthreads();

    {
        float* oC = outC + (size_t)bt * 16384;
        bf16x8 a = ldsb8(W2A + (w*16 + l16) * 40 + l4*8);
#pragma unroll
        for (int dt = 0; dt < 16; ++dt) {
            bf16x8 b = ldsb8(TCM + (dt*16 + l16) * 40 + l4*8);
            f32x4 acc = {};
            acc = __builtin_amdgcn_mfma_f32_16x16x32_bf16(a, b, acc, 0, 0, 0);
#pragma unroll
            for (int i = 0; i < 4; ++i) {
                int ag = w*16 + l4*4 + i;
                float m = (float)MK[ag];
                oC[ag * 256 + dt*16 + l16] = acc[i] * m;
            }
        }
    }
}

extern "C" void kernel_launch(void* const* d_in, const int* in_sizes, int n_in,
                              void* d_out, int out_size, void* d_ws, size_t ws_size,
                              hipStream_t stream) {
    (void)in_sizes; (void)n_in; (void)out_size; (void)ws_size;
    const float* obs   = (const float*)d_in[0];
    const int*   amask = (const int*)d_in[1];
    const float* W1    = (const float*)d_in[2];
    const float* b1    = (const float*)d_in[3];
    const float* W2    = (const float*)d_in[4];
    const float* b2    = (const float*)d_in[5];
    const float* W3    = (const float*)d_in[6];
    const float* b3    = (const float*)d_in[7];
    const float* tq    = (const float*)d_in[8];

    unsigned short* wt1 = (unsigned short*)d_ws;       // 4  chunks x 16384 us
    unsigned short* wt2 = wt1 + 65536;                 // 16 chunks x 16384 us
    unsigned short* wt3 = wt2 + 262144;                // 16 chunks x 8192 us

    float* outT = (float*)d_out;
    float* outC = outT + (size_t)BT_TOTAL * 16 * 256;
    unsigned short* embWS = (unsigned short*)outC;     // emb staged in outC region

    prep_weights<<<36, 512, 0, stream>>>(W1, W2, W3, wt1, wt2, wt3);
    mlp_kernel<<<BT_TOTAL, 1024, K1_LDS, stream>>>(
        obs, wt1, b1, wt2, b2, wt3, b3, embWS);
    attn_kernel<<<BT_TOTAL, 256, K2_LDS, stream>>>(
        amask, tq, embWS, outT, outC);
}

// Round 12
// 120.300 us; speedup vs baseline: 1.4863x; 1.4863x over previous
//
#include <hip/hip_runtime.h>
#include <hip/hip_bf16.h>

#define BT_TOTAL 1024

typedef __bf16 bf16x8 __attribute__((ext_vector_type(8)));
typedef float  f32x4  __attribute__((ext_vector_type(4)));
typedef int    i32x4  __attribute__((ext_vector_type(4)));
typedef short  s16x4  __attribute__((ext_vector_type(4)));

__device__ inline unsigned short f2bf(float f) {
    unsigned int u = __builtin_bit_cast(unsigned int, f);
    u = (u + 0x7FFFu + ((u >> 16) & 1u)) >> 16;
    return (unsigned short)u;
}

__device__ inline bf16x8 ldsb8(const unsigned short* p) {
    i32x4 t = *(const i32x4*)p;
    return __builtin_bit_cast(bf16x8, t);
}

__device__ __forceinline__ void gl_lds16(const void* g, void* l) {
    __builtin_amdgcn_global_load_lds(
        (const __attribute__((address_space(1))) void*)g,
        (__attribute__((address_space(3))) void*)l, 16, 0, 0);
}

// Per-wave sync, NO in-loop s_barrier (B slices are wave-private: stage region
// == read region; H is read-only inside K-loops; layer handoffs use full
// __syncthreads). sched_barrier(0) after every asm wait = rule-18 fence
// (prevents hipcc hoisting MFMA/ds_read across the waitcnt).
#define STEP_PRE() do { \
    asm volatile("s_waitcnt lgkmcnt(0)" ::: "memory"); \
    __builtin_amdgcn_sched_barrier(0); } while (0)
#define WAITV4() do { \
    asm volatile("s_waitcnt vmcnt(4)" ::: "memory"); \
    __builtin_amdgcn_sched_barrier(0); } while (0)
#define WAITV2() do { \
    asm volatile("s_waitcnt vmcnt(2)" ::: "memory"); \
    __builtin_amdgcn_sched_barrier(0); } while (0)
#define WAITV0() do { \
    asm volatile("s_waitcnt vmcnt(0)" ::: "memory"); \
    __builtin_amdgcn_sched_barrier(0); } while (0)

// swizzled byte offset of element (n, kl) inside a [N][32] bf16 chunk
__device__ __forceinline__ int swz_off(int n, int kl) {
    return ((n >> 1) << 7) + ((((n & 1) << 6) | (kl << 1)) ^ (((n >> 1) & 7) << 4));
}

template<int CALLS>
__device__ __forceinline__ void stage_tile(const void* chunk, char* dst, int wv, int lane) {
#pragma unroll
    for (int c = 0; c < CALLS; ++c) {
        int off = wv * (CALLS * 1024) + c * 1024;   // wave-private slice == read region
        gl_lds16((const char*)chunk + off + lane * 16, dst + off);
    }
}

// ---------------- prep: weights -> swizzled bf16 chunks (verified) ----------------
__global__ __launch_bounds__(512) void prep_weights(
    const float* __restrict__ W1, const float* __restrict__ W2,
    const float* __restrict__ W3,
    unsigned short* __restrict__ wt1, unsigned short* __restrict__ wt2,
    unsigned short* __restrict__ wt3)
{
    int b = blockIdx.x, tid = threadIdx.x;
    if (b < 4) {                    // L1: K=128, N=512
        int k0 = b * 32;
        unsigned short* d = wt1 + b * 16384;
        for (int kl = 0; kl < 32; ++kl) {
            int n = tid;
            float v = W1[(size_t)(k0 + kl) * 512 + n];
            d[swz_off(n, kl) >> 1] = f2bf(v);
        }
    } else if (b < 20) {            // L2: K=512, N=512
        int c = b - 4, k0 = c * 32;
        unsigned short* d = wt2 + c * 16384;
        for (int kl = 0; kl < 32; ++kl) {
            int n = tid;
            float v = W2[(size_t)(k0 + kl) * 512 + n];
            d[swz_off(n, kl) >> 1] = f2bf(v);
        }
    } else {                        // L3: K=512, N=256 (16 chunks)
        int c = b - 20, k0 = c * 32;
        unsigned short* d = wt3 + c * 8192;
        for (int i = 0; i < 16; ++i) {
            int e = i * 512 + tid;
            int kl = e >> 8, n = e & 255;
            float v = W3[(size_t)(k0 + kl) * 256 + n];
            d[swz_off(n, kl) >> 1] = f2bf(v);
        }
    }
}

// ======================= K1: fused MLP, barrier-free K-loops + A-prefetch =======================
// LDS: OBS [64][136]us @0 (17408) ; H [64][520]us @17408 (66560) ;
//      B0 @83968 (32768) ; B1 @116736 (32768)  -> 149504
#define K1_LDS 149504

__global__ __launch_bounds__(512, 2) void mlp_kernel(
    const float* __restrict__ obs,
    const unsigned short* __restrict__ C1, const float* __restrict__ b1,
    const unsigned short* __restrict__ C2, const float* __restrict__ b2,
    const unsigned short* __restrict__ C3, const float* __restrict__ b3,
    unsigned short* __restrict__ embOut)   // per bt: RM [64][256] then CM [256][64]
{
    extern __shared__ __align__(16) char smem[];
    unsigned short* OBS = (unsigned short*)smem;            // [64][136]
    unsigned short* H   = (unsigned short*)(smem + 17408);  // [64][520]
    char* B0 = smem + 83968;
    char* B1 = smem + 116736;
    unsigned short* EMB = (unsigned short*)smem;            // [64][264] (post)

    const int bt = blockIdx.x, tid = threadIdx.x;
    const int lane = tid & 63, wv = tid >> 6;   // 8 waves
    const int l16 = lane & 15, l4 = lane >> 4;

    int boff[4], boff3[2];
#pragma unroll
    for (int nt = 0; nt < 4; ++nt) {
        int n = wv * 64 + nt * 16 + l16;
        boff[nt] = ((n >> 1) << 7) + ((((n & 1) << 6) | (l4 << 4)) ^ (((n >> 1) & 7) << 4));
    }
#pragma unroll
    for (int nt = 0; nt < 2; ++nt) {
        int n = wv * 32 + nt * 16 + l16;
        boff3[nt] = ((n >> 1) << 7) + ((((n & 1) << 6) | (l4 << 4)) ^ (((n >> 1) & 7) << 4));
    }

    // ---- pre-load ALL biases into registers (no vmem in K-loops except staging) ----
    float bias1[4], bias2[4], bias3[2];
#pragma unroll
    for (int nt = 0; nt < 4; ++nt) {
        bias1[nt] = b1[wv * 64 + nt * 16 + l16];
        bias2[nt] = b2[wv * 64 + nt * 16 + l16];
    }
#pragma unroll
    for (int nt = 0; nt < 2; ++nt) bias3[nt] = b3[wv * 32 + nt * 16 + l16];

    // ---- prologue: stage L1 tile 0; convert obs -> bf16 LDS ----
    stage_tile<4>(C1, B0, wv, lane);
    {
        const f32x4* src = (const f32x4*)(obs + (size_t)bt * 8192);
#pragma unroll
        for (int i = 0; i < 4; ++i) {
            int idx = tid + i * 512;
            f32x4 v = src[idx];
            int row = idx >> 5, c4 = idx & 31;
            s16x4 s;
            s[0] = (short)f2bf(v.x); s[1] = (short)f2bf(v.y);
            s[2] = (short)f2bf(v.z); s[3] = (short)f2bf(v.w);
            *(s16x4*)(OBS + row * 136 + c4 * 4) = s;
        }
    }
    __syncthreads();   // full drain: biases, obs, stage(0) complete; OBS stable

    // ---- L1: 4 steps (A from OBS LDS; r10-proven) ----
    f32x4 acc1[4][4] = {};
    for (int t = 0; t < 4; ++t) {
        STEP_PRE();
        if (t < 3) stage_tile<4>(C1 + (size_t)(t + 1) * 16384, (t & 1) ? B0 : B1, wv, lane);
        else       stage_tile<4>(C2, B0, wv, lane);
        WAITV4();
        const char* bb = (t & 1) ? B1 : B0;
        bf16x8 afr[4], bfr[4];
#pragma unroll
        for (int mt = 0; mt < 4; ++mt)
            afr[mt] = ldsb8(OBS + (mt * 16 + l16) * 136 + t * 32 + l4 * 8);
#pragma unroll
        for (int nt = 0; nt < 4; ++nt)
            bfr[nt] = ldsb8((const unsigned short*)(bb + boff[nt]));
#pragma unroll
        for (int nt = 0; nt < 4; ++nt)
#pragma unroll
            for (int mt = 0; mt < 4; ++mt)
                acc1[mt][nt] = __builtin_amdgcn_mfma_f32_16x16x32_bf16(afr[mt], bfr[nt], acc1[mt][nt], 0, 0, 0);
    }
    {
#pragma unroll
        for (int nt = 0; nt < 4; ++nt) {
            int col = wv * 64 + nt * 16 + l16;
#pragma unroll
            for (int mt = 0; mt < 4; ++mt)
#pragma unroll
                for (int i = 0; i < 4; ++i) {
                    int row = mt * 16 + l4 * 4 + i;
                    H[row * 520 + col] = f2bf(fmaxf(acc1[mt][nt][i] + bias1[nt], 0.f));
                }
        }
    }
    __syncthreads();   // H1 visible; drains C2-tile0 stage

    // ---- L2: 16 steps, A(t+1) prefetched cross-step ----
    f32x4 acc2[4][4] = {};
    {
        bf16x8 afr[4];
#pragma unroll
        for (int mt = 0; mt < 4; ++mt)
            afr[mt] = ldsb8(H + (mt * 16 + l16) * 520 + l4 * 8);   // A(0)
        for (int t = 0; t < 16; ++t) {
            STEP_PRE();    // A(t) + B(t-1) reads landed (WAR for stage target)
            if (t < 15) { stage_tile<4>(C2 + (size_t)(t + 1) * 16384, (t & 1) ? B0 : B1, wv, lane); WAITV4(); }
            else        { stage_tile<2>(C3, B0, wv, lane);                                          WAITV2(); }
            const char* bb = (t & 1) ? B1 : B0;
            bf16x8 bfr[4], afn[4];
#pragma unroll
            for (int nt = 0; nt < 4; ++nt)
                bfr[nt] = ldsb8((const unsigned short*)(bb + boff[nt]));
            int tn = (t + 1) & 15;
#pragma unroll
            for (int mt = 0; mt < 4; ++mt)
                afn[mt] = ldsb8(H + (mt * 16 + l16) * 520 + tn * 32 + l4 * 8);
#pragma unroll
            for (int nt = 0; nt < 4; ++nt)
#pragma unroll
                for (int mt = 0; mt < 4; ++mt)
                    acc2[mt][nt] = __builtin_amdgcn_mfma_f32_16x16x32_bf16(afr[mt], bfr[nt], acc2[mt][nt], 0, 0, 0);
#pragma unroll
            for (int mt = 0; mt < 4; ++mt) afr[mt] = afn[mt];
        }
    }
    __syncthreads();   // all H1 reads done before overwrite; drains C3-tile0
    {
#pragma unroll
        for (int nt = 0; nt < 4; ++nt) {
            int col = wv * 64 + nt * 16 + l16;
#pragma unroll
            for (int mt = 0; mt < 4; ++mt)
#pragma unroll
                for (int i = 0; i < 4; ++i) {
                    int row = mt * 16 + l4 * 4 + i;
                    H[row * 520 + col] = f2bf(fmaxf(acc2[mt][nt][i] + bias2[nt], 0.f));
                }
        }
    }
    __syncthreads();   // H2 visible

    // ---- L3: 16 steps (K=512), N=256, A(t+1) prefetched ----
    f32x4 acc3[4][2] = {};
    {
        bf16x8 afr[4];
#pragma unroll
        for (int mt = 0; mt < 4; ++mt)
            afr[mt] = ldsb8(H + (mt * 16 + l16) * 520 + l4 * 8);   // A(0)
        for (int t = 0; t < 16; ++t) {
            STEP_PRE();
            if (t < 15) { stage_tile<2>(C3 + (size_t)(t + 1) * 8192, (t & 1) ? B0 : B1, wv, lane); WAITV2(); }
            else        { WAITV0(); }
            const char* bb = (t & 1) ? B1 : B0;
            bf16x8 bfr[2], afn[4];
#pragma unroll
            for (int nt = 0; nt < 2; ++nt)
                bfr[nt] = ldsb8((const unsigned short*)(bb + boff3[nt]));
            int tn = (t + 1) & 15;
#pragma unroll
            for (int mt = 0; mt < 4; ++mt)
                afn[mt] = ldsb8(H + (mt * 16 + l16) * 520 + tn * 32 + l4 * 8);
#pragma unroll
            for (int nt = 0; nt < 2; ++nt)
#pragma unroll
                for (int mt = 0; mt < 4; ++mt)
                    acc3[mt][nt] = __builtin_amdgcn_mfma_f32_16x16x32_bf16(afr[mt], bfr[nt], acc3[mt][nt], 0, 0, 0);
#pragma unroll
            for (int mt = 0; mt < 4; ++mt) afr[mt] = afn[mt];
        }
    }
    __syncthreads();   // all H/OBS reads done; EMB overlay writable

    // ---- emb epilogue: bf16 tile in LDS, then global RM + CM writes ----
    {
#pragma unroll
        for (int nt = 0; nt < 2; ++nt) {
            int col = wv * 32 + nt * 16 + l16;
#pragma unroll
            for (int mt = 0; mt < 4; ++mt)
#pragma unroll
                for (int i = 0; i < 4; ++i) {
                    int row = mt * 16 + l4 * 4 + i;
                    EMB[row * 264 + col] = f2bf(acc3[mt][nt][i] + bias3[nt]);
                }
        }
    }
    __syncthreads();
    {
        unsigned short* eR = embOut + (size_t)bt * 32768;
        unsigned short* eC = eR + 16384;
        // RM: [64][256] = 2048 x 16B groups (coalesced)
#pragma unroll
        for (int u = 0; u < 4; ++u) {
            int uu = tid + u * 512;                 // 0..2047
            int row = uu >> 5, c8 = (uu & 31) * 8;
            i32x4 v = *(const i32x4*)(EMB + row * 264 + c8);
            *(i32x4*)(eR + uu * 8) = v;             // eR[row*256 + c8]
        }
        // CM: lane <-> column-consecutive (2-way LDS reads, free)
#pragma unroll
        for (int u = 0; u < 4; ++u) {
            int v = tid + u * 512;                  // 0..2047
            int col = v & 255, rg = v >> 8;
            i32x4 w;
#pragma unroll
            for (int j = 0; j < 4; ++j) {
                unsigned int a = EMB[(rg * 8 + 2 * j) * 264 + col];
                unsigned int b = EMB[(rg * 8 + 2 * j + 1) * 264 + col];
                w[j] = (int)(a | (b << 16));
            }
            *(i32x4*)(eC + col * 64 + rg * 8) = w;  // eC[col*64 + rg*8]
        }
    }
}

// ======================= K2: attention (unchanged, verified) =======================
// LDS: W1A [16][72]us @0 (2304) ; TCM [256][40]us @2304 (20480) ;
//      TF [16][260]f32 @22784 (16640) ; W2A [64][40]us @39424 (5120) ;
//      MK [64]i32 @44544 (256) ; SMX/SSM @44800 (512) ; TQ [16][264]us @45312 (8448)
#define K2_LDS 53760

__global__ void attn_kernel(const int* __restrict__ amask,
                            const float* __restrict__ tq,
                            const unsigned short* __restrict__ emb,
                            float* __restrict__ outT, float* __restrict__ outC)
{
    extern __shared__ __align__(16) char smem[];
    unsigned short* W1A = (unsigned short*)smem;
    unsigned short* TCM = (unsigned short*)(smem + 2304);
    float*          TF  = (float*)(smem + 22784);
    unsigned short* W2A = (unsigned short*)(smem + 39424);
    int*            MK  = (int*)(smem + 44544);
    float*          SMX = (float*)(smem + 44800);
    float*          SSM = SMX + 64;
    unsigned short* TQ  = (unsigned short*)(smem + 45312);  // [16][264]

    const int bt = blockIdx.x, tid = threadIdx.x;
    const int lane = tid & 63, w = tid >> 6;
    const int l16 = lane & 15, l4 = lane >> 4;
    const unsigned short* eR = emb + (size_t)bt * 32768;
    const unsigned short* eC = eR + 16384;

    if (tid < 64) MK[tid] = amask[(size_t)bt * 64 + tid];
#pragma unroll
    for (int i = 0; i < 16; ++i) {
        int idx = tid + i * 256;
        int row = idx >> 8, col = idx & 255;
        TQ[row * 264 + col] = f2bf(tq[idx]);
    }
    __syncthreads();

    float sv[4]; int msk;
    {
        f32x4 acc = {};
#pragma unroll
        for (int kk = 0; kk < 8; ++kk) {
            int ko = kk*32 + l4*8;
            bf16x8 a = ldsb8(TQ + l16 * 264 + ko);
            bf16x8 b = ldsb8(eR + (w*16 + l16) * 256 + ko);
            acc = __builtin_amdgcn_mfma_f32_16x16x32_bf16(a, b, acc, 0, 0, 0);
        }
        msk = MK[w*16 + l16];
#pragma unroll
        for (int i = 0; i < 4; ++i) sv[i] = msk ? acc[i] * 0.0625f : -3.0e38f;
        float mx[4];
#pragma unroll
        for (int i = 0; i < 4; ++i) {
            float m = sv[i];
#pragma unroll
            for (int off = 1; off < 16; off <<= 1) m = fmaxf(m, __shfl_xor(m, off, 16));
            mx[i] = m;
        }
        if (l16 == 0) {
#pragma unroll
            for (int i = 0; i < 4; ++i) SMX[(l4*4 + i) * 4 + w] = mx[i];
        }
    }
    __syncthreads();
    float ev[4];
    {
#pragma unroll
        for (int i = 0; i < 4; ++i) {
            int q = l4*4 + i;
            float g = fmaxf(fmaxf(SMX[q*4+0], SMX[q*4+1]), fmaxf(SMX[q*4+2], SMX[q*4+3]));
            ev[i] = msk ? __expf(sv[i] - g) : 0.f;
            float s = ev[i];
#pragma unroll
            for (int off = 1; off < 16; off <<= 1) s += __shfl_xor(s, off, 16);
            if (l16 == 0) SSM[q*4 + w] = s;
        }
    }
    __syncthreads();
    {
#pragma unroll
        for (int i = 0; i < 4; ++i) {
            int q = l4*4 + i;
            float tot = SSM[q*4+0] + SSM[q*4+1] + SSM[q*4+2] + SSM[q*4+3];
            float w1 = ev[i] * (1.0f / fmaxf(tot, 1e-8f));
            W1A[q * 72 + w*16 + l16] = f2bf(w1);
        }
    }
    __syncthreads();

    {
        bf16x8 bW[2];
#pragma unroll
        for (int kk = 0; kk < 2; ++kk) bW[kk] = ldsb8(W1A + l16 * 72 + kk*32 + l4*8);
#pragma unroll
        for (int p = 0; p < 4; ++p) {
            int dt = w + p * 4;
            f32x4 acc = {};
#pragma unroll
            for (int kk = 0; kk < 2; ++kk) {
                bf16x8 a = ldsb8(eC + (dt*16 + l16) * 64 + kk*32 + l4*8);
                acc = __builtin_amdgcn_mfma_f32_16x16x32_bf16(a, bW[kk], acc, 0, 0, 0);
            }
#pragma unroll
            for (int i = 0; i < 4; ++i) {
                int d = dt*16 + l4*4 + i;
                TCM[d * 40 + l16]      = f2bf(acc[i]);
                TCM[d * 40 + 16 + l16] = 0;
                TF[l16 * 260 + d]      = acc[i];
            }
        }
    }
    __syncthreads();

    {
        float* oT = outT + (size_t)bt * 4096;
#pragma unroll
        for (int it = 0; it < 16; ++it) {
            int idx = tid + it * 256;
            oT[idx] = TF[(idx >> 8) * 260 + (idx & 255)];
        }
    }

    {
        f32x4 acc = {};
#pragma unroll
        for (int kk = 0; kk < 8; ++kk) {
            int ko = kk*32 + l4*8;
            bf16x8 a = ldsb8(eR + (w*16 + l16) * 256 + ko);
            const float* tp = TF + l16 * 260 + ko;
            f32x4 t0 = *(const f32x4*)tp;
            f32x4 t1 = *(const f32x4*)(tp + 4);
            bf16x8 b;
            b[0]=(__bf16)t0.x; b[1]=(__bf16)t0.y; b[2]=(__bf16)t0.z; b[3]=(__bf16)t0.w;
            b[4]=(__bf16)t1.x; b[5]=(__bf16)t1.y; b[6]=(__bf16)t1.z; b[7]=(__bf16)t1.w;
            acc = __builtin_amdgcn_mfma_f32_16x16x32_bf16(a, b, acc, 0, 0, 0);
        }
#pragma unroll
        for (int i = 0; i < 4; ++i) {
            float s = acc[i] * 0.0625f;
            float m = s;
#pragma unroll
            for (int off = 1; off < 16; off <<= 1) m = fmaxf(m, __shfl_xor(m, off, 16));
            float e = __expf(s - m);
            float su = e;
#pragma unroll
            for (int off = 1; off < 16; off <<= 1) su += __shfl_xor(su, off, 16);
            float w2 = e / su;
            int ag = w*16 + l4*4 + i;
            W2A[ag * 40 + l16]      = f2bf(w2);
            W2A[ag * 40 + 16 + l16] = 0;
        }
    }
    __syncthreads();

    {
        float* oC = outC + (size_t)bt * 16384;
        bf16x8 a = ldsb8(W2A + (w*16 + l16) * 40 + l4*8);
#pragma unroll
        for (int dt = 0; dt < 16; ++dt) {
            bf16x8 b = ldsb8(TCM + (dt*16 + l16) * 40 + l4*8);
            f32x4 acc = {};
            acc = __builtin_amdgcn_mfma_f32_16x16x32_bf16(a, b, acc, 0, 0, 0);
#pragma unroll
            for (int i = 0; i < 4; ++i) {
                int ag = w*16 + l4*4 + i;
                float m = (float)MK[ag];
                oC[ag * 256 + dt*16 + l16] = acc[i] * m;
            }
        }
    }
}

extern "C" void kernel_launch(void* const* d_in, const int* in_sizes, int n_in,
                              void* d_out, int out_size, void* d_ws, size_t ws_size,
                              hipStream_t stream) {
    (void)in_sizes; (void)n_in; (void)out_size; (void)ws_size;
    const float* obs   = (const float*)d_in[0];
    const int*   amask = (const int*)d_in[1];
    const float* W1    = (const float*)d_in[2];
    const float* b1    = (const float*)d_in[3];
    const float* W2    = (const float*)d_in[4];
    const float* b2    = (const float*)d_in[5];
    const float* W3    = (const float*)d_in[6];
    const float* b3    = (const float*)d_in[7];
    const float* tq    = (const float*)d_in[8];

    unsigned short* wt1 = (unsigned short*)d_ws;       // 4  chunks x 16384 us
    unsigned short* wt2 = wt1 + 65536;                 // 16 chunks x 16384 us
    unsigned short* wt3 = wt2 + 262144;                // 16 chunks x 8192 us

    float* outT = (float*)d_out;
    float* outC = outT + (size_t)BT_TOTAL * 16 * 256;
    unsigned short* embWS = (unsigned short*)outC;     // emb staged in outC region

    prep_weights<<<36, 512, 0, stream>>>(W1, W2, W3, wt1, wt2, wt3);
    mlp_kernel<<<BT_TOTAL, 512, K1_LDS, stream>>>(
        obs, wt1, b1, wt2, b2, wt3, b3, embWS);
    attn_kernel<<<BT_TOTAL, 256, K2_LDS, stream>>>(
        amask, tq, embWS, outT, outC);
}

// Round 14
// 119.149 us; speedup vs baseline: 1.5006x; 1.0097x over previous
//
#include <hip/hip_runtime.h>
#include <hip/hip_bf16.h>

#define BT_TOTAL 1024

typedef __bf16 bf16x8 __attribute__((ext_vector_type(8)));
typedef float  f32x4  __attribute__((ext_vector_type(4)));
typedef int    i32x4  __attribute__((ext_vector_type(4)));
typedef short  s16x4  __attribute__((ext_vector_type(4)));

__device__ inline unsigned short f2bf(float f) {
    unsigned int u = __builtin_bit_cast(unsigned int, f);
    u = (u + 0x7FFFu + ((u >> 16) & 1u)) >> 16;
    return (unsigned short)u;
}

__device__ inline bf16x8 ldsb8(const unsigned short* p) {
    i32x4 t = *(const i32x4*)p;
    return __builtin_bit_cast(bf16x8, t);
}

__device__ __forceinline__ void gl_lds16(const void* g, void* l) {
    __builtin_amdgcn_global_load_lds(
        (const __attribute__((address_space(1))) void*)g,
        (__attribute__((address_space(3))) void*)l, 16, 0, 0);
}

#define SB0() __builtin_amdgcn_sched_barrier(0)

// Per-wave sync, no in-loop s_barrier (r12-proven). sched_barrier(0) after
// every asm wait = rule-18 fence.
// STEP_PRE0: full LDS drain (L1).
// STEP_PRE4: leave newest 4 LDS reads (the afn prefetch) in flight. SAFE ONLY
// because an explicit SB0 between bfr and afn issue pins queue order
// [bfr..., afn...] -> lgkmcnt(4) retires exactly the bfr reads (r13 race fix).
#define STEP_PRE0() do { \
    asm volatile("s_waitcnt lgkmcnt(0)" ::: "memory"); SB0(); } while (0)
#define STEP_PRE4() do { \
    asm volatile("s_waitcnt lgkmcnt(4)" ::: "memory"); SB0(); } while (0)
#define WAITV4() do { \
    asm volatile("s_waitcnt vmcnt(4)" ::: "memory"); SB0(); } while (0)
#define WAITV2() do { \
    asm volatile("s_waitcnt vmcnt(2)" ::: "memory"); SB0(); } while (0)
#define WAITV0() do { \
    asm volatile("s_waitcnt vmcnt(0)" ::: "memory"); SB0(); } while (0)

// swizzled byte offset of element (n, kl) inside a [N][32] bf16 chunk
__device__ __forceinline__ int swz_off(int n, int kl) {
    return ((n >> 1) << 7) + ((((n & 1) << 6) | (kl << 1)) ^ (((n >> 1) & 7) << 4));
}

template<int CALLS>
__device__ __forceinline__ void stage_tile(const void* chunk, char* dst, int wv, int lane) {
#pragma unroll
    for (int c = 0; c < CALLS; ++c) {
        int off = wv * (CALLS * 1024) + c * 1024;   // wave-private slice == read region
        gl_lds16((const char*)chunk + off + lane * 16, dst + off);
    }
}

// ---------------- prep: weights -> swizzled bf16 chunks (verified) ----------------
__global__ __launch_bounds__(512) void prep_weights(
    const float* __restrict__ W1, const float* __restrict__ W2,
    const float* __restrict__ W3,
    unsigned short* __restrict__ wt1, unsigned short* __restrict__ wt2,
    unsigned short* __restrict__ wt3)
{
    int b = blockIdx.x, tid = threadIdx.x;
    if (b < 4) {                    // L1: K=128, N=512
        int k0 = b * 32;
        unsigned short* d = wt1 + b * 16384;
        for (int kl = 0; kl < 32; ++kl) {
            int n = tid;
            float v = W1[(size_t)(k0 + kl) * 512 + n];
            d[swz_off(n, kl) >> 1] = f2bf(v);
        }
    } else if (b < 20) {            // L2: K=512, N=512
        int c = b - 4, k0 = c * 32;
        unsigned short* d = wt2 + c * 16384;
        for (int kl = 0; kl < 32; ++kl) {
            int n = tid;
            float v = W2[(size_t)(k0 + kl) * 512 + n];
            d[swz_off(n, kl) >> 1] = f2bf(v);
        }
    } else {                        // L3: K=512, N=256 (16 chunks)
        int c = b - 20, k0 = c * 32;
        unsigned short* d = wt3 + c * 8192;
        for (int i = 0; i < 16; ++i) {
            int e = i * 512 + tid;
            int kl = e >> 8, n = e & 255;
            float v = W3[(size_t)(k0 + kl) * 256 + n];
            d[swz_off(n, kl) >> 1] = f2bf(v);
        }
    }
}

// ======================= K1: fused MLP (C^T accum, vectorized epilogues) =======================
// LDS: OBS [64][136]us @0 (17408) ; H [64][520]us @17408 (66560) ;
//      B0 @83968 (32768) ; B1 @116736 (32768)  -> 149504
#define K1_LDS 149504

__global__ __launch_bounds__(512, 2) void mlp_kernel(
    const float* __restrict__ obs,
    const unsigned short* __restrict__ C1, const float* __restrict__ b1,
    const unsigned short* __restrict__ C2, const float* __restrict__ b2,
    const unsigned short* __restrict__ C3, const float* __restrict__ b3,
    unsigned short* __restrict__ embOut)   // per bt: RM [64][256] then CM [256][64]
{
    extern __shared__ __align__(16) char smem[];
    unsigned short* OBS = (unsigned short*)smem;            // [64][136]
    unsigned short* H   = (unsigned short*)(smem + 17408);  // [64][520]
    char* B0 = smem + 83968;
    char* B1 = smem + 116736;
    unsigned short* EMB = (unsigned short*)smem;            // [64][264] (post)

    const int bt = blockIdx.x, tid = threadIdx.x;
    const int lane = tid & 63, wv = tid >> 6;   // 8 waves
    const int l16 = lane & 15, l4 = lane >> 4;

    int boff[4], boff3[2];
#pragma unroll
    for (int nt = 0; nt < 4; ++nt) {
        int n = wv * 64 + nt * 16 + l16;
        boff[nt] = ((n >> 1) << 7) + ((((n & 1) << 6) | (l4 << 4)) ^ (((n >> 1) & 7) << 4));
    }
#pragma unroll
    for (int nt = 0; nt < 2; ++nt) {
        int n = wv * 32 + nt * 16 + l16;
        boff3[nt] = ((n >> 1) << 7) + ((((n & 1) << 6) | (l4 << 4)) ^ (((n >> 1) & 7) << 4));
    }

    // ---- prologue: stage L1 tile 0; convert obs -> bf16 LDS ----
    stage_tile<4>(C1, B0, wv, lane);
    {
        const f32x4* src = (const f32x4*)(obs + (size_t)bt * 8192);
#pragma unroll
        for (int i = 0; i < 4; ++i) {
            int idx = tid + i * 512;
            f32x4 v = src[idx];
            int row = idx >> 5, c4 = idx & 31;
            s16x4 s;
            s[0] = (short)f2bf(v.x); s[1] = (short)f2bf(v.y);
            s[2] = (short)f2bf(v.z); s[3] = (short)f2bf(v.w);
            *(s16x4*)(OBS + row * 136 + c4 * 4) = s;
        }
    }
    __syncthreads();   // full drain: obs + stage(0) complete; OBS stable

    // ---- L1: 4 steps ----
    // mfma(bfr, afr, acc) computes C^T: acc[i] -> (col n = l4*4+i, row m = l16)
    f32x4 acc1[4][4] = {};
    for (int t = 0; t < 4; ++t) {
        STEP_PRE0();
        if (t < 3) stage_tile<4>(C1 + (size_t)(t + 1) * 16384, (t & 1) ? B0 : B1, wv, lane);
        else       stage_tile<4>(C2, B0, wv, lane);
        WAITV4();
        const char* bb = (t & 1) ? B1 : B0;
        bf16x8 afr[4], bfr[4];
#pragma unroll
        for (int mt = 0; mt < 4; ++mt)
            afr[mt] = ldsb8(OBS + (mt * 16 + l16) * 136 + t * 32 + l4 * 8);
#pragma unroll
        for (int nt = 0; nt < 4; ++nt)
            bfr[nt] = ldsb8((const unsigned short*)(bb + boff[nt]));
#pragma unroll
        for (int nt = 0; nt < 4; ++nt)
#pragma unroll
            for (int mt = 0; mt < 4; ++mt)
                acc1[mt][nt] = __builtin_amdgcn_mfma_f32_16x16x32_bf16(bfr[nt], afr[mt], acc1[mt][nt], 0, 0, 0);
    }
    // epilogue: H = relu(acc1^T + b1) — 4 consecutive cols per thread -> b64 writes
    {
        f32x4 bv[4];
#pragma unroll
        for (int nt = 0; nt < 4; ++nt)
            bv[nt] = *(const f32x4*)(b1 + wv * 64 + nt * 16 + l4 * 4);
#pragma unroll
        for (int mt = 0; mt < 4; ++mt) {
            int row = mt * 16 + l16;
#pragma unroll
            for (int nt = 0; nt < 4; ++nt) {
                f32x4 v = acc1[mt][nt] + bv[nt];
                s16x4 s;
#pragma unroll
                for (int i = 0; i < 4; ++i) s[i] = (short)f2bf(fmaxf(v[i], 0.f));
                *(s16x4*)(H + row * 520 + wv * 64 + nt * 16 + l4 * 4) = s;
            }
        }
    }
    __syncthreads();   // H1 visible; drains C2-tile0 stage + bias loads

    // ---- L2: 16 steps, A(t+1) prefetched cross-step (order-pinned) ----
    f32x4 acc2[4][4] = {};
    {
        bf16x8 afr[4];
#pragma unroll
        for (int mt = 0; mt < 4; ++mt)
            afr[mt] = ldsb8(H + (mt * 16 + l16) * 520 + l4 * 8);   // A(0)
        for (int t = 0; t < 16; ++t) {
            STEP_PRE4();   // retires bfr(t-1) (oldest); afn(t) stays in flight
            if (t < 15) { stage_tile<4>(C2 + (size_t)(t + 1) * 16384, (t & 1) ? B0 : B1, wv, lane); WAITV4(); }
            else        { stage_tile<2>(C3, B0, wv, lane);                                          WAITV2(); }
            const char* bb = (t & 1) ? B1 : B0;
            bf16x8 bfr[4], afn[4];
#pragma unroll
            for (int nt = 0; nt < 4; ++nt)
                bfr[nt] = ldsb8((const unsigned short*)(bb + boff[nt]));
            SB0();         // PIN ORDER: bfr issued before afn (r13 race fix)
            int tn = (t + 1) & 15;
#pragma unroll
            for (int mt = 0; mt < 4; ++mt)
                afn[mt] = ldsb8(H + (mt * 16 + l16) * 520 + tn * 32 + l4 * 8);
#pragma unroll
            for (int nt = 0; nt < 4; ++nt)
#pragma unroll
                for (int mt = 0; mt < 4; ++mt)
                    acc2[mt][nt] = __builtin_amdgcn_mfma_f32_16x16x32_bf16(bfr[nt], afr[mt], acc2[mt][nt], 0, 0, 0);
#pragma unroll
            for (int mt = 0; mt < 4; ++mt) afr[mt] = afn[mt];
        }
    }
    __syncthreads();   // all H1 reads done before overwrite; drains C3-tile0
    {
        f32x4 bv[4];
#pragma unroll
        for (int nt = 0; nt < 4; ++nt)
            bv[nt] = *(const f32x4*)(b2 + wv * 64 + nt * 16 + l4 * 4);
#pragma unroll
        for (int mt = 0; mt < 4; ++mt) {
            int row = mt * 16 + l16;
#pragma unroll
            for (int nt = 0; nt < 4; ++nt) {
                f32x4 v = acc2[mt][nt] + bv[nt];
                s16x4 s;
#pragma unroll
                for (int i = 0; i < 4; ++i) s[i] = (short)f2bf(fmaxf(v[i], 0.f));
                *(s16x4*)(H + row * 520 + wv * 64 + nt * 16 + l4 * 4) = s;
            }
        }
    }
    __syncthreads();   // H2 visible

    // ---- L3: 16 steps (K=512), N=256, A(t+1) prefetched (order-pinned) ----
    f32x4 acc3[4][2] = {};
    {
        bf16x8 afr[4];
#pragma unroll
        for (int mt = 0; mt < 4; ++mt)
            afr[mt] = ldsb8(H + (mt * 16 + l16) * 520 + l4 * 8);   // A(0)
        for (int t = 0; t < 16; ++t) {
            STEP_PRE4();   // queue [bfr(t-1)x2, afn(t)x4] -> retires the 2 bfr
            if (t < 15) { stage_tile<2>(C3 + (size_t)(t + 1) * 8192, (t & 1) ? B0 : B1, wv, lane); WAITV2(); }
            else        { WAITV0(); }
            const char* bb = (t & 1) ? B1 : B0;
            bf16x8 bfr[2], afn[4];
#pragma unroll
            for (int nt = 0; nt < 2; ++nt)
                bfr[nt] = ldsb8((const unsigned short*)(bb + boff3[nt]));
            SB0();         // PIN ORDER: bfr before afn
            int tn = (t + 1) & 15;
#pragma unroll
            for (int mt = 0; mt < 4; ++mt)
                afn[mt] = ldsb8(H + (mt * 16 + l16) * 520 + tn * 32 + l4 * 8);
#pragma unroll
            for (int nt = 0; nt < 2; ++nt)
#pragma unroll
                for (int mt = 0; mt < 4; ++mt)
                    acc3[mt][nt] = __builtin_amdgcn_mfma_f32_16x16x32_bf16(bfr[nt], afr[mt], acc3[mt][nt], 0, 0, 0);
#pragma unroll
            for (int mt = 0; mt < 4; ++mt) afr[mt] = afn[mt];
        }
    }
    __syncthreads();   // all H/OBS reads done; EMB overlay writable

    // ---- emb epilogue: bf16 tile in LDS (b64 writes), then global RM + CM ----
    {
        f32x4 bv[2];
#pragma unroll
        for (int nt = 0; nt < 2; ++nt)
            bv[nt] = *(const f32x4*)(b3 + wv * 32 + nt * 16 + l4 * 4);
#pragma unroll
        for (int mt = 0; mt < 4; ++mt) {
            int row = mt * 16 + l16;
#pragma unroll
            for (int nt = 0; nt < 2; ++nt) {
                f32x4 v = acc3[mt][nt] + bv[nt];
                s16x4 s;
#pragma unroll
                for (int i = 0; i < 4; ++i) s[i] = (short)f2bf(v[i]);
                *(s16x4*)(EMB + row * 264 + wv * 32 + nt * 16 + l4 * 4) = s;
            }
        }
    }
    __syncthreads();
    {
        unsigned short* eR = embOut + (size_t)bt * 32768;
        unsigned short* eC = eR + 16384;
        // RM: [64][256] = 2048 x 16B groups (coalesced)
#pragma unroll
        for (int u = 0; u < 4; ++u) {
            int uu = tid + u * 512;                 // 0..2047
            int row = uu >> 5, c8 = (uu & 31) * 8;
            i32x4 v = *(const i32x4*)(EMB + row * 264 + c8);
            *(i32x4*)(eR + uu * 8) = v;             // eR[row*256 + c8]
        }
        // CM: lane <-> column-consecutive (2-way LDS reads, free)
#pragma unroll
        for (int u = 0; u < 4; ++u) {
            int v = tid + u * 512;                  // 0..2047
            int col = v & 255, rg = v >> 8;
            i32x4 w;
#pragma unroll
            for (int j = 0; j < 4; ++j) {
                unsigned int a = EMB[(rg * 8 + 2 * j) * 264 + col];
                unsigned int b = EMB[(rg * 8 + 2 * j + 1) * 264 + col];
                w[j] = (int)(a | (b << 16));
            }
            *(i32x4*)(eC + col * 64 + rg * 8) = w;  // eC[col*64 + rg*8]
        }
    }
}

// ======================= K2: attention (unchanged, verified) =======================
// LDS: W1A [16][72]us @0 (2304) ; TCM [256][40]us @2304 (20480) ;
//      TF [16][260]f32 @22784 (16640) ; W2A [64][40]us @39424 (5120) ;
//      MK [64]i32 @44544 (256) ; SMX/SSM @44800 (512) ; TQ [16][264]us @45312 (8448)
#define K2_LDS 53760

__global__ void attn_kernel(const int* __restrict__ amask,
                            const float* __restrict__ tq,
                            const unsigned short* __restrict__ emb,
                            float* __restrict__ outT, float* __restrict__ outC)
{
    extern __shared__ __align__(16) char smem[];
    unsigned short* W1A = (unsigned short*)smem;
    unsigned short* TCM = (unsigned short*)(smem + 2304);
    float*          TF  = (float*)(smem + 22784);
    unsigned short* W2A = (unsigned short*)(smem + 39424);
    int*            MK  = (int*)(smem + 44544);
    float*          SMX = (float*)(smem + 44800);
    float*          SSM = SMX + 64;
    unsigned short* TQ  = (unsigned short*)(smem + 45312);  // [16][264]

    const int bt = blockIdx.x, tid = threadIdx.x;
    const int lane = tid & 63, w = tid >> 6;
    const int l16 = lane & 15, l4 = lane >> 4;
    const unsigned short* eR = emb + (size_t)bt * 32768;
    const unsigned short* eC = eR + 16384;

    if (tid < 64) MK[tid] = amask[(size_t)bt * 64 + tid];
#pragma unroll
    for (int i = 0; i < 16; ++i) {
        int idx = tid + i * 256;
        int row = idx >> 8, col = idx & 255;
        TQ[row * 264 + col] = f2bf(tq[idx]);
    }
    __syncthreads();

    float sv[4]; int msk;
    {
        f32x4 acc = {};
#pragma unroll
        for (int kk = 0; kk < 8; ++kk) {
            int ko = kk*32 + l4*8;
            bf16x8 a = ldsb8(TQ + l16 * 264 + ko);
            bf16x8 b = ldsb8(eR + (w*16 + l16) * 256 + ko);
            acc = __builtin_amdgcn_mfma_f32_16x16x32_bf16(a, b, acc, 0, 0, 0);
        }
        msk = MK[w*16 + l16];
#pragma unroll
        for (int i = 0; i < 4; ++i) sv[i] = msk ? acc[i] * 0.0625f : -3.0e38f;
        float mx[4];
#pragma unroll
        for (int i = 0; i < 4; ++i) {
            float m = sv[i];
#pragma unroll
            for (int off = 1; off < 16; off <<= 1) m = fmaxf(m, __shfl_xor(m, off, 16));
            mx[i] = m;
        }
        if (l16 == 0) {
#pragma unroll
            for (int i = 0; i < 4; ++i) SMX[(l4*4 + i) * 4 + w] = mx[i];
        }
    }
    __syncthreads();
    float ev[4];
    {
#pragma unroll
        for (int i = 0; i < 4; ++i) {
            int q = l4*4 + i;
            float g = fmaxf(fmaxf(SMX[q*4+0], SMX[q*4+1]), fmaxf(SMX[q*4+2], SMX[q*4+3]));
            ev[i] = msk ? __expf(sv[i] - g) : 0.f;
            float s = ev[i];
#pragma unroll
            for (int off = 1; off < 16; off <<= 1) s += __shfl_xor(s, off, 16);
            if (l16 == 0) SSM[q*4 + w] = s;
        }
    }
    __syncthreads();
    {
#pragma unroll
        for (int i = 0; i < 4; ++i) {
            int q = l4*4 + i;
            float tot = SSM[q*4+0] + SSM[q*4+1] + SSM[q*4+2] + SSM[q*4+3];
            float w1 = ev[i] * (1.0f / fmaxf(tot, 1e-8f));
            W1A[q * 72 + w*16 + l16] = f2bf(w1);
        }
    }
    __syncthreads();

    {
        bf16x8 bW[2];
#pragma unroll
        for (int kk = 0; kk < 2; ++kk) bW[kk] = ldsb8(W1A + l16 * 72 + kk*32 + l4*8);
#pragma unroll
        for (int p = 0; p < 4; ++p) {
            int dt = w + p * 4;
            f32x4 acc = {};
#pragma unroll
            for (int kk = 0; kk < 2; ++kk) {
                bf16x8 a = ldsb8(eC + (dt*16 + l16) * 64 + kk*32 + l4*8);
                acc = __builtin_amdgcn_mfma_f32_16x16x32_bf16(a, bW[kk], acc, 0, 0, 0);
            }
#pragma unroll
            for (int i = 0; i < 4; ++i) {
                int d = dt*16 + l4*4 + i;
                TCM[d * 40 + l16]      = f2bf(acc[i]);
                TCM[d * 40 + 16 + l16] = 0;
                TF[l16 * 260 + d]      = acc[i];
            }
        }
    }
    __syncthreads();

    {
        float* oT = outT + (size_t)bt * 4096;
#pragma unroll
        for (int it = 0; it < 16; ++it) {
            int idx = tid + it * 256;
            oT[idx] = TF[(idx >> 8) * 260 + (idx & 255)];
        }
    }

    {
        f32x4 acc = {};
#pragma unroll
        for (int kk = 0; kk < 8; ++kk) {
            int ko = kk*32 + l4*8;
            bf16x8 a = ldsb8(eR + (w*16 + l16) * 256 + ko);
            const float* tp = TF + l16 * 260 + ko;
            f32x4 t0 = *(const f32x4*)tp;
            f32x4 t1 = *(const f32x4*)(tp + 4);
            bf16x8 b;
            b[0]=(__bf16)t0.x; b[1]=(__bf16)t0.y; b[2]=(__bf16)t0.z; b[3]=(__bf16)t0.w;
            b[4]=(__bf16)t1.x; b[5]=(__bf16)t1.y; b[6]=(__bf16)t1.z; b[7]=(__bf16)t1.w;
            acc = __builtin_amdgcn_mfma_f32_16x16x32_bf16(a, b, acc, 0, 0, 0);
        }
#pragma unroll
        for (int i = 0; i < 4; ++i) {
            float s = acc[i] * 0.0625f;
            float m = s;
#pragma unroll
            for (int off = 1; off < 16; off <<= 1) m = fmaxf(m, __shfl_xor(m, off, 16));
            float e = __expf(s - m);
            float su = e;
#pragma unroll
            for (int off = 1; off < 16; off <<= 1) su += __shfl_xor(su, off, 16);
            float w2 = e / su;
            int ag = w*16 + l4*4 + i;
            W2A[ag * 40 + l16]      = f2bf(w2);
            W2A[ag * 40 + 16 + l16] = 0;
        }
    }
    __syncthreads();

    {
        float* oC = outC + (size_t)bt * 16384;
        bf16x8 a = ldsb8(W2A + (w*16 + l16) * 40 + l4*8);
#pragma unroll
        for (int dt = 0; dt < 16; ++dt) {
            bf16x8 b = ldsb8(TCM + (dt*16 + l16) * 40 + l4*8);
            f32x4 acc = {};
            acc = __builtin_amdgcn_mfma_f32_16x16x32_bf16(a, b, acc, 0, 0, 0);
#pragma unroll
            for (int i = 0; i < 4; ++i) {
                int ag = w*16 + l4*4 + i;
                float m = (float)MK[ag];
                oC[ag * 256 + dt*16 + l16] = acc[i] * m;
            }
        }
    }
}

extern "C" void kernel_launch(void* const* d_in, const int* in_sizes, int n_in,
                              void* d_out, int out_size, void* d_ws, size_t ws_size,
                              hipStream_t stream) {
    (void)in_sizes; (void)n_in; (void)out_size; (void)ws_size;
    const float* obs   = (const float*)d_in[0];
    const int*   amask = (const int*)d_in[1];
    const float* W1    = (const float*)d_in[2];
    const float* b1    = (const float*)d_in[3];
    const float* W2    = (const float*)d_in[4];
    const float* b2    = (const float*)d_in[5];
    const float* W3    = (const float*)d_in[6];
    const float* b3    = (const float*)d_in[7];
    const float* tq    = (const float*)d_in[8];

    unsigned short* wt1 = (unsigned short*)d_ws;       // 4  chunks x 16384 us
    unsigned short* wt2 = wt1 + 65536;                 // 16 chunks x 16384 us
    unsigned short* wt3 = wt2 + 262144;                // 16 chunks x 8192 us

    float* outT = (float*)d_out;
    float* outC = outT + (size_t)BT_TOTAL * 16 * 256;
    unsigned short* embWS = (unsigned short*)outC;     // emb staged in outC region

    prep_weights<<<36, 512, 0, stream>>>(W1, W2, W3, wt1, wt2, wt3);
    mlp_kernel<<<BT_TOTAL, 512, K1_LDS, stream>>>(
        obs, wt1, b1, wt2, b2, wt3, b3, embWS);
    attn_kernel<<<BT_TOTAL, 256, K2_LDS, stream>>>(
        amask, tq, embWS, outT, outC);
}

// Round 15
// 101.064 us; speedup vs baseline: 1.7691x; 1.1789x over previous
//
#include <hip/hip_runtime.h>
#include <hip/hip_bf16.h>

#define BT_TOTAL 1024

typedef __bf16 bf16x8 __attribute__((ext_vector_type(8)));
typedef float  f32x4  __attribute__((ext_vector_type(4)));
typedef int    i32x4  __attribute__((ext_vector_type(4)));
typedef short  s16x4  __attribute__((ext_vector_type(4)));

__device__ inline unsigned short f2bf(float f) {
    unsigned int u = __builtin_bit_cast(unsigned int, f);
    u = (u + 0x7FFFu + ((u >> 16) & 1u)) >> 16;
    return (unsigned short)u;
}

__device__ inline bf16x8 ldsb8(const unsigned short* p) {
    i32x4 t = *(const i32x4*)p;
    return __builtin_bit_cast(bf16x8, t);
}

#define SB0() __builtin_amdgcn_sched_barrier(0)

// Counted vmcnt waits. SAFE: the ONLY vmem ops inside K-loops are our asm
// loads (biases/epilogue loads sit outside, drained by __syncthreads).
// SB0 after each wait = rule-18 fence (MFMA can't hoist past the asm wait).
#define WAITV4() do { \
    asm volatile("s_waitcnt vmcnt(4)" ::: "memory"); SB0(); } while (0)
#define WAITV2() do { \
    asm volatile("s_waitcnt vmcnt(2)" ::: "memory"); SB0(); } while (0)
#define WAITV0() do { \
    asm volatile("s_waitcnt vmcnt(0)" ::: "memory"); SB0(); } while (0)

// global -> VGPR, saddr form: 32-bit voffset (VGPR) + SGPR base + imm offset.
// asm volatile: cannot be sunk/folded/reordered vs other asm (r8/r9 fix).
#define GLOAD4(d, vo, sb, IMM) \
    asm volatile("global_load_dwordx4 %0, %1, %2 offset:" IMM \
                 : "=v"(d) : "v"(vo), "s"(sb) : "memory")

// ---------------- prep: fragment-direct pack (r9-verified layout) ----------------
// chunk t (BK=32), wave wv slice contiguous; lane l's 16B at
// slice + c*1024B + l*16B == B-fragment c (n = wv*Wc + c*16 + (l&15),
// k = t*32 + (l>>4)*8 .. +8).
__global__ __launch_bounds__(512) void prep_pack(
    const float* __restrict__ W1, const float* __restrict__ W2,
    const float* __restrict__ W3,
    unsigned short* __restrict__ wt1, unsigned short* __restrict__ wt2,
    unsigned short* __restrict__ wt3)
{
    int p = blockIdx.x * 512 + threadIdx.x;      // 0 .. 458751
    const float* src; unsigned short* dst; int N_, Wc;
    if (p < 65536)       { src = W1; dst = wt1; N_ = 512; Wc = 64; }
    else if (p < 327680) { p -= 65536;  src = W2; dst = wt2; N_ = 512; Wc = 64; }
    else                 { p -= 327680; src = W3; dst = wt3; N_ = 256; Wc = 32; }
    int k = p / N_, n = p % N_;
    int t = k >> 5, kk = k & 31, l4 = kk >> 3, j = kk & 7;
    int wv = n / Wc, nc = n % Wc, nt = nc >> 4, l16 = nc & 15;
    int off = t * (N_ * 32) + wv * (Wc * 32) + nt * 512 + (l4 * 16 + l16) * 8 + j;
    dst[off] = f2bf(src[(size_t)k * N_ + n]);
}

// ======================= K1: fused MLP — B in registers, A via LDS =======================
// LDS: H [64][520]us = 66560 only -> 2 blocks/CU. obs staged into H cols 0..127
// for L1 (freed by sync before L1 epilogue). EMB overlay [64][264]us @0 post-L3.
#define K1_LDS 66560

__global__ __launch_bounds__(512, 4) void mlp_kernel(
    const float* __restrict__ obs,
    const unsigned short* __restrict__ C1, const float* __restrict__ b1,
    const unsigned short* __restrict__ C2, const float* __restrict__ b2,
    const unsigned short* __restrict__ C3, const float* __restrict__ b3,
    unsigned short* __restrict__ embOut)   // per bt: RM [64][256] then CM [256][64]
{
    extern __shared__ __align__(16) char smem[];
    unsigned short* H   = (unsigned short*)smem;   // [64][520]
    unsigned short* EMB = (unsigned short*)smem;   // [64][264] (post-L3 overlay)

    const int bt = blockIdx.x, tid = threadIdx.x;
    const int lane = tid & 63, wv = tid >> 6;   // 8 waves
    const int l16 = lane & 15, l4 = lane >> 4;

    const int voff  = wv * 4096 + lane * 16;    // L1/L2 slice: 64 cols * 32 k * 2B
    const int voff3 = wv * 2048 + lane * 16;    // L3 slice: 32 cols

    i32x4 breg[2][4];

    // ---- prologue: issue B1(0); stage obs -> H cols 0..127 (bf16) ----
    GLOAD4(breg[0][0], voff, C1, "0");
    GLOAD4(breg[0][1], voff, C1, "1024");
    GLOAD4(breg[0][2], voff, C1, "2048");
    GLOAD4(breg[0][3], voff, C1, "3072");
    {
        const f32x4* src = (const f32x4*)(obs + (size_t)bt * 8192);
#pragma unroll
        for (int i = 0; i < 4; ++i) {
            int idx = tid + i * 512;            // 0..2047
            f32x4 v = src[idx];
            int row = idx >> 5, c4 = idx & 31;
            s16x4 s;
            s[0] = (short)f2bf(v.x); s[1] = (short)f2bf(v.y);
            s[2] = (short)f2bf(v.z); s[3] = (short)f2bf(v.w);
            *(s16x4*)(H + row * 520 + c4 * 4) = s;
        }
    }
    __syncthreads();   // drains obs loads + B1(0); H cols 0..127 = obs bf16

    // ---- L1: 4 steps; A from H cols 0..127 ----
    // mfma(b, a, acc) computes C^T: acc[i] -> (col n = l4*4+i, row m = l16)
    f32x4 acc1[4][4] = {};
#pragma unroll
    for (int t = 0; t < 4; ++t) {
        if (t < 3) {
            const unsigned short* sb = C1 + (size_t)(t + 1) * 16384;
            GLOAD4(breg[(t + 1) & 1][0], voff, sb, "0");
            GLOAD4(breg[(t + 1) & 1][1], voff, sb, "1024");
            GLOAD4(breg[(t + 1) & 1][2], voff, sb, "2048");
            GLOAD4(breg[(t + 1) & 1][3], voff, sb, "3072");
            WAITV4();
        } else WAITV0();
        bf16x8 afr[4];
#pragma unroll
        for (int mt = 0; mt < 4; ++mt)
            afr[mt] = ldsb8(H + (mt * 16 + l16) * 520 + t * 32 + l4 * 8);
#pragma unroll
        for (int nt = 0; nt < 4; ++nt) {
            bf16x8 bq = __builtin_bit_cast(bf16x8, breg[t & 1][nt]);
#pragma unroll
            for (int mt = 0; mt < 4; ++mt)
                acc1[mt][nt] = __builtin_amdgcn_mfma_f32_16x16x32_bf16(bq, afr[mt], acc1[mt][nt], 0, 0, 0);
        }
    }
    __syncthreads();   // ALL waves' obs reads done before H overwrite
    // epilogue: H = relu(acc1^T + b1); issue B2(0) before the publishing sync
    {
        f32x4 bv[4];
#pragma unroll
        for (int nt = 0; nt < 4; ++nt)
            bv[nt] = *(const f32x4*)(b1 + wv * 64 + nt * 16 + l4 * 4);
#pragma unroll
        for (int mt = 0; mt < 4; ++mt) {
            int row = mt * 16 + l16;
#pragma unroll
            for (int nt = 0; nt < 4; ++nt) {
                f32x4 v = acc1[mt][nt] + bv[nt];
                s16x4 s;
#pragma unroll
                for (int i = 0; i < 4; ++i) s[i] = (short)f2bf(fmaxf(v[i], 0.f));
                *(s16x4*)(H + row * 520 + wv * 64 + nt * 16 + l4 * 4) = s;
            }
        }
    }
    GLOAD4(breg[0][0], voff, C2, "0");
    GLOAD4(breg[0][1], voff, C2, "1024");
    GLOAD4(breg[0][2], voff, C2, "2048");
    GLOAD4(breg[0][3], voff, C2, "3072");
    __syncthreads();   // H1 visible; B2(0) drained

    // ---- L2: 16 steps ----
    f32x4 acc2[4][4] = {};
#pragma unroll
    for (int t = 0; t < 16; ++t) {
        if (t < 15) {
            const unsigned short* sb = C2 + (size_t)(t + 1) * 16384;
            GLOAD4(breg[(t + 1) & 1][0], voff, sb, "0");
            GLOAD4(breg[(t + 1) & 1][1], voff, sb, "1024");
            GLOAD4(breg[(t + 1) & 1][2], voff, sb, "2048");
            GLOAD4(breg[(t + 1) & 1][3], voff, sb, "3072");
            WAITV4();
        } else WAITV0();
        bf16x8 afr[4];
#pragma unroll
        for (int mt = 0; mt < 4; ++mt)
            afr[mt] = ldsb8(H + (mt * 16 + l16) * 520 + t * 32 + l4 * 8);
#pragma unroll
        for (int nt = 0; nt < 4; ++nt) {
            bf16x8 bq = __builtin_bit_cast(bf16x8, breg[t & 1][nt]);
#pragma unroll
            for (int mt = 0; mt < 4; ++mt)
                acc2[mt][nt] = __builtin_amdgcn_mfma_f32_16x16x32_bf16(bq, afr[mt], acc2[mt][nt], 0, 0, 0);
        }
    }
    __syncthreads();   // all H1 reads done before overwrite
    {
        f32x4 bv[4];
#pragma unroll
        for (int nt = 0; nt < 4; ++nt)
            bv[nt] = *(const f32x4*)(b2 + wv * 64 + nt * 16 + l4 * 4);
#pragma unroll
        for (int mt = 0; mt < 4; ++mt) {
            int row = mt * 16 + l16;
#pragma unroll
            for (int nt = 0; nt < 4; ++nt) {
                f32x4 v = acc2[mt][nt] + bv[nt];
                s16x4 s;
#pragma unroll
                for (int i = 0; i < 4; ++i) s[i] = (short)f2bf(fmaxf(v[i], 0.f));
                *(s16x4*)(H + row * 520 + wv * 64 + nt * 16 + l4 * 4) = s;
            }
        }
    }
    GLOAD4(breg[0][0], voff3, C3, "0");
    GLOAD4(breg[0][1], voff3, C3, "1024");
    __syncthreads();   // H2 visible; B3(0) drained

    // ---- L3: 16 steps (K=512), N=256 ----
    f32x4 acc3[4][2] = {};
#pragma unroll
    for (int t = 0; t < 16; ++t) {
        if (t < 15) {
            const unsigned short* sb = C3 + (size_t)(t + 1) * 8192;
            GLOAD4(breg[(t + 1) & 1][0], voff3, sb, "0");
            GLOAD4(breg[(t + 1) & 1][1], voff3, sb, "1024");
            WAITV2();
        } else WAITV0();
        bf16x8 afr[4];
#pragma unroll
        for (int mt = 0; mt < 4; ++mt)
            afr[mt] = ldsb8(H + (mt * 16 + l16) * 520 + t * 32 + l4 * 8);
#pragma unroll
        for (int nt = 0; nt < 2; ++nt) {
            bf16x8 bq = __builtin_bit_cast(bf16x8, breg[t & 1][nt]);
#pragma unroll
            for (int mt = 0; mt < 4; ++mt)
                acc3[mt][nt] = __builtin_amdgcn_mfma_f32_16x16x32_bf16(bq, afr[mt], acc3[mt][nt], 0, 0, 0);
        }
    }
    __syncthreads();   // all H reads done; EMB overlay writable

    // ---- emb epilogue: bf16 tile in LDS (b64 writes), then global RM + CM ----
    {
        f32x4 bv[2];
#pragma unroll
        for (int nt = 0; nt < 2; ++nt)
            bv[nt] = *(const f32x4*)(b3 + wv * 32 + nt * 16 + l4 * 4);
#pragma unroll
        for (int mt = 0; mt < 4; ++mt) {
            int row = mt * 16 + l16;
#pragma unroll
            for (int nt = 0; nt < 2; ++nt) {
                f32x4 v = acc3[mt][nt] + bv[nt];
                s16x4 s;
#pragma unroll
                for (int i = 0; i < 4; ++i) s[i] = (short)f2bf(v[i]);
                *(s16x4*)(EMB + row * 264 + wv * 32 + nt * 16 + l4 * 4) = s;
            }
        }
    }
    __syncthreads();
    {
        unsigned short* eR = embOut + (size_t)bt * 32768;
        unsigned short* eC = eR + 16384;
        // RM: [64][256] = 2048 x 16B groups (coalesced)
#pragma unroll
        for (int u = 0; u < 4; ++u) {
            int uu = tid + u * 512;                 // 0..2047
            int row = uu >> 5, c8 = (uu & 31) * 8;
            i32x4 v = *(const i32x4*)(EMB + row * 264 + c8);
            *(i32x4*)(eR + uu * 8) = v;             // eR[row*256 + c8]
        }
        // CM: lane <-> column-consecutive (2-way LDS reads, free)
#pragma unroll
        for (int u = 0; u < 4; ++u) {
            int v = tid + u * 512;                  // 0..2047
            int col = v & 255, rg = v >> 8;
            i32x4 w;
#pragma unroll
            for (int j = 0; j < 4; ++j) {
                unsigned int a = EMB[(rg * 8 + 2 * j) * 264 + col];
                unsigned int b = EMB[(rg * 8 + 2 * j + 1) * 264 + col];
                w[j] = (int)(a | (b << 16));
            }
            *(i32x4*)(eC + col * 64 + rg * 8) = w;  // eC[col*64 + rg*8]
        }
    }
}

// ======================= K2: attention (unchanged, verified) =======================
// LDS: W1A [16][72]us @0 (2304) ; TCM [256][40]us @2304 (20480) ;
//      TF [16][260]f32 @22784 (16640) ; W2A [64][40]us @39424 (5120) ;
//      MK [64]i32 @44544 (256) ; SMX/SSM @44800 (512) ; TQ [16][264]us @45312 (8448)
#define K2_LDS 53760

__global__ void attn_kernel(const int* __restrict__ amask,
                            const float* __restrict__ tq,
                            const unsigned short* __restrict__ emb,
                            float* __restrict__ outT, float* __restrict__ outC)
{
    extern __shared__ __align__(16) char smem[];
    unsigned short* W1A = (unsigned short*)smem;
    unsigned short* TCM = (unsigned short*)(smem + 2304);
    float*          TF  = (float*)(smem + 22784);
    unsigned short* W2A = (unsigned short*)(smem + 39424);
    int*            MK  = (int*)(smem + 44544);
    float*          SMX = (float*)(smem + 44800);
    float*          SSM = SMX + 64;
    unsigned short* TQ  = (unsigned short*)(smem + 45312);  // [16][264]

    const int bt = blockIdx.x, tid = threadIdx.x;
    const int lane = tid & 63, w = tid >> 6;
    const int l16 = lane & 15, l4 = lane >> 4;
    const unsigned short* eR = emb + (size_t)bt * 32768;
    const unsigned short* eC = eR + 16384;

    if (tid < 64) MK[tid] = amask[(size_t)bt * 64 + tid];
#pragma unroll
    for (int i = 0; i < 16; ++i) {
        int idx = tid + i * 256;
        int row = idx >> 8, col = idx & 255;
        TQ[row * 264 + col] = f2bf(tq[idx]);
    }
    __syncthreads();

    float sv[4]; int msk;
    {
        f32x4 acc = {};
#pragma unroll
        for (int kk = 0; kk < 8; ++kk) {
            int ko = kk*32 + l4*8;
            bf16x8 a = ldsb8(TQ + l16 * 264 + ko);
            bf16x8 b = ldsb8(eR + (w*16 + l16) * 256 + ko);
            acc = __builtin_amdgcn_mfma_f32_16x16x32_bf16(a, b, acc, 0, 0, 0);
        }
        msk = MK[w*16 + l16];
#pragma unroll
        for (int i = 0; i < 4; ++i) sv[i] = msk ? acc[i] * 0.0625f : -3.0e38f;
        float mx[4];
#pragma unroll
        for (int i = 0; i < 4; ++i) {
            float m = sv[i];
#pragma unroll
            for (int off = 1; off < 16; off <<= 1) m = fmaxf(m, __shfl_xor(m, off, 16));
            mx[i] = m;
        }
        if (l16 == 0) {
#pragma unroll
            for (int i = 0; i < 4; ++i) SMX[(l4*4 + i) * 4 + w] = mx[i];
        }
    }
    __syncthreads();
    float ev[4];
    {
#pragma unroll
        for (int i = 0; i < 4; ++i) {
            int q = l4*4 + i;
            float g = fmaxf(fmaxf(SMX[q*4+0], SMX[q*4+1]), fmaxf(SMX[q*4+2], SMX[q*4+3]));
            ev[i] = msk ? __expf(sv[i] - g) : 0.f;
            float s = ev[i];
#pragma unroll
            for (int off = 1; off < 16; off <<= 1) s += __shfl_xor(s, off, 16);
            if (l16 == 0) SSM[q*4 + w] = s;
        }
    }
    __syncthreads();
    {
#pragma unroll
        for (int i = 0; i < 4; ++i) {
            int q = l4*4 + i;
            float tot = SSM[q*4+0] + SSM[q*4+1] + SSM[q*4+2] + SSM[q*4+3];
            float w1 = ev[i] * (1.0f / fmaxf(tot, 1e-8f));
            W1A[q * 72 + w*16 + l16] = f2bf(w1);
        }
    }
    __syncthreads();

    {
        bf16x8 bW[2];
#pragma unroll
        for (int kk = 0; kk < 2; ++kk) bW[kk] = ldsb8(W1A + l16 * 72 + kk*32 + l4*8);
#pragma unroll
        for (int p = 0; p < 4; ++p) {
            int dt = w + p * 4;
            f32x4 acc = {};
#pragma unroll
            for (int kk = 0; kk < 2; ++kk) {
                bf16x8 a = ldsb8(eC + (dt*16 + l16) * 64 + kk*32 + l4*8);
                acc = __builtin_amdgcn_mfma_f32_16x16x32_bf16(a, bW[kk], acc, 0, 0, 0);
            }
#pragma unroll
            for (int i = 0; i < 4; ++i) {
                int d = dt*16 + l4*4 + i;
                TCM[d * 40 + l16]      = f2bf(acc[i]);
                TCM[d * 40 + 16 + l16] = 0;
                TF[l16 * 260 + d]      = acc[i];
            }
        }
    }
    __syncthreads();

    {
        float* oT = outT + (size_t)bt * 4096;
#pragma unroll
        for (int it = 0; it < 16; ++it) {
            int idx = tid + it * 256;
            oT[idx] = TF[(idx >> 8) * 260 + (idx & 255)];
        }
    }

    {
        f32x4 acc = {};
#pragma unroll
        for (int kk = 0; kk < 8; ++kk) {
            int ko = kk*32 + l4*8;
            bf16x8 a = ldsb8(eR + (w*16 + l16) * 256 + ko);
            const float* tp = TF + l16 * 260 + ko;
            f32x4 t0 = *(const f32x4*)tp;
            f32x4 t1 = *(const f32x4*)(tp + 4);
            bf16x8 b;
            b[0]=(__bf16)t0.x; b[1]=(__bf16)t0.y; b[2]=(__bf16)t0.z; b[3]=(__bf16)t0.w;
            b[4]=(__bf16)t1.x; b[5]=(__bf16)t1.y; b[6]=(__bf16)t1.z; b[7]=(__bf16)t1.w;
            acc = __builtin_amdgcn_mfma_f32_16x16x32_bf16(a, b, acc, 0, 0, 0);
        }
#pragma unroll
        for (int i = 0; i < 4; ++i) {
            float s = acc[i] * 0.0625f;
            float m = s;
#pragma unroll
            for (int off = 1; off < 16; off <<= 1) m = fmaxf(m, __shfl_xor(m, off, 16));
            float e = __expf(s - m);
            float su = e;
#pragma unroll
            for (int off = 1; off < 16; off <<= 1) su += __shfl_xor(su, off, 16);
            float w2 = e / su;
            int ag = w*16 + l4*4 + i;
            W2A[ag * 40 + l16]      = f2bf(w2);
            W2A[ag * 40 + 16 + l16] = 0;
        }
    }
    __syncthreads();

    {
        float* oC = outC + (size_t)bt * 16384;
        bf16x8 a = ldsb8(W2A + (w*16 + l16) * 40 + l4*8);
#pragma unroll
        for (int dt = 0; dt < 16; ++dt) {
            bf16x8 b = ldsb8(TCM + (dt*16 + l16) * 40 + l4*8);
            f32x4 acc = {};
            acc = __builtin_amdgcn_mfma_f32_16x16x32_bf16(a, b, acc, 0, 0, 0);
#pragma unroll
            for (int i = 0; i < 4; ++i) {
                int ag = w*16 + l4*4 + i;
                float m = (float)MK[ag];
                oC[ag * 256 + dt*16 + l16] = acc[i] * m;
            }
        }
    }
}

extern "C" void kernel_launch(void* const* d_in, const int* in_sizes, int n_in,
                              void* d_out, int out_size, void* d_ws, size_t ws_size,
                              hipStream_t stream) {
    (void)in_sizes; (void)n_in; (void)out_size; (void)ws_size;
    const float* obs   = (const float*)d_in[0];
    const int*   amask = (const int*)d_in[1];
    const float* W1    = (const float*)d_in[2];
    const float* b1    = (const float*)d_in[3];
    const float* W2    = (const float*)d_in[4];
    const float* b2    = (const float*)d_in[5];
    const float* W3    = (const float*)d_in[6];
    const float* b3    = (const float*)d_in[7];
    const float* tq    = (const float*)d_in[8];

    unsigned short* wt1 = (unsigned short*)d_ws;       // 65536 elems (frag-packed)
    unsigned short* wt2 = wt1 + 65536;                 // 262144 elems
    unsigned short* wt3 = wt2 + 262144;                // 131072 elems

    float* outT = (float*)d_out;
    float* outC = outT + (size_t)BT_TOTAL * 16 * 256;
    unsigned short* embWS = (unsigned short*)outC;     // emb staged in outC region

    prep_pack<<<896, 512, 0, stream>>>(W1, W2, W3, wt1, wt2, wt3);
    mlp_kernel<<<BT_TOTAL, 512, K1_LDS, stream>>>(
        obs, wt1, b1, wt2, b2, wt3, b3, embWS);
    attn_kernel<<<BT_TOTAL, 256, K2_LDS, stream>>>(
        amask, tq, embWS, outT, outC);
}